// Round 15
// baseline (218.900 us; speedup 1.0000x reference)
//
#include <hip/hip_runtime.h>
#include <cstddef>

typedef __attribute__((ext_vector_type(8))) _Float16 half8;
typedef __attribute__((ext_vector_type(4))) float f32x4;
typedef __attribute__((ext_vector_type(4))) unsigned short us4;

#define TT 16
#define APAD 72                 // shorts per (row,col) slot: 144 B
#define A_TILE (3*34*APAD)      // fallback-kernel tile: 7344 shorts
#define CHUNK  8192             // shorts per 16KB weight chunk
#define NB     6                // B reg-pipeline slots
#define PF     5                // prefetch distance (< NB)
#define XNB    4                // B reg-pipeline slots (xconv)
#define XPF    3                // xconv prefetch distance (< XNB)

__device__ __forceinline__ unsigned short f2h(float f) {
    return __builtin_bit_cast(unsigned short, (_Float16)f);
}
__device__ __forceinline__ float h2f(unsigned short u) {
    return (float)__builtin_bit_cast(_Float16, u);
}
__device__ __forceinline__ float hsig(float z) {
    return fminf(fmaxf(0.2f * z + 0.5f, 0.f), 1.f);
}

// Weight pack (fp16): Wc short idx i = (s*4 + kg)*2048 + n*8 + j, s in [0,36)
// s<18 -> Wx chunk sub=s ; s>=18 -> Wh chunk sub=s-18
__global__ __launch_bounds__(256) void prep_kernel(
    const float* __restrict__ Wx, const float* __restrict__ Wh,
    const float* __restrict__ gamma, const float* __restrict__ beta,
    const float* __restrict__ mean, const float* __restrict__ var,
    unsigned short* __restrict__ Wc, float* __restrict__ bn)
{
    if (blockIdx.x == 1152) {
        if (threadIdx.x < 64) {
            const int c = threadIdx.x;
            const float inv = gamma[c] * rsqrtf(var[c] + 1e-3f);
            bn[c] = inv;
            bn[64 + c] = beta[c] - mean[c] * inv;
        }
        return;
    }
    const int i = blockIdx.x * 256 + threadIdx.x;   // < 294912
    const int j  = i & 7;
    const int n  = (i >> 3) & 255;
    const int kg = (i >> 11) & 3;
    const int s  = i >> 13;            // 0..35
    const int sub = s % 18;
    const float* W = (s >= 18) ? Wh : Wx;
    const int k5 = sub * 32 + kg * 8 + j;
    const int c = k5 & 63, q = k5 >> 6;
    const int kx = q % 3, ky = q / 3;
    Wc[i] = f2h(W[(size_t)((ky * 3 + kx) * 64 + c) * 256 + n]);
}

// B-frag register loads: chunk ci, this lane's pair (nf=0 at boff, nf=1 at +128)
#define BLOAD(slot, ci) {                                                     \
    const unsigned short* _p = Wc + (size_t)(ci) * CHUNK + boff;              \
    bp[slot][0] = *(const half8*)_p;                                          \
    bp[slot][1] = *(const half8*)(_p + 128);                                  \
}

// 18-chunk conv pass (fallback fused kernel), B from reg pipeline.
template<int C0, int CLAST, int AOFF>
__device__ __forceinline__ void conv_pass18(
    const unsigned short* __restrict__ Wc, const int boff,
    half8 (&bp)[NB][2],
    const unsigned short* abase,
    f32x4 acc[2][2])
{
    #pragma unroll
    for (int sub = 0; sub < 18; ++sub) {
        const int ci = C0 + sub;
        if (ci + PF <= CLAST) BLOAD((ci + PF) % NB, ci + PF)

        const int ky = sub / 6, kx = (sub / 2) % 3, cb = sub & 1;
        const half8 b0 = bp[ci % NB][0];
        const half8 b1 = bp[ci % NB][1];
        const unsigned short* at = abase + AOFF + (ky * 34 + kx) * APAD + cb * 32;
        const half8 a0 = *(const half8*)(at);
        const half8 a1 = *(const half8*)(at + 16 * APAD);
        acc[0][0] = __builtin_amdgcn_mfma_f32_16x16x32_f16(a0, b0, acc[0][0], 0, 0, 0);
        acc[0][1] = __builtin_amdgcn_mfma_f32_16x16x32_f16(a0, b1, acc[0][1], 0, 0, 0);
        acc[1][0] = __builtin_amdgcn_mfma_f32_16x16x32_f16(a1, b0, acc[1][0], 0, 0, 0);
        acc[1][1] = __builtin_amdgcn_mfma_f32_16x16x32_f16(a1, b1, acc[1][1], 0, 0, 0);
    }
}

// Hoisted x-conv, 1 row/block (round-13 proven version, linear APAD layout).
// record vi = ((((n*16+t)*64+y)*2+xh)*8+w)*64+lane -> 16 shorts [mfc][nf][j].
__global__ __launch_bounds__(512) void xconv_kernel(
    const float* __restrict__ x,
    const unsigned short* __restrict__ Wc,
    const float* __restrict__ bias,
    unsigned short* __restrict__ xg)
{
    const int bid0 = blockIdx.x;
    const int bid = (bid0 & 7) * 256 + (bid0 >> 3);  // bijective XCD swizzle (2048=8*256)
    const int y = bid & 63;
    const int t = (bid >> 6) & 15;
    const int n = bid >> 10;
    const int tid = threadIdx.x, lane = tid & 63, w = tid >> 6;
    const int p0 = lane & 15, g = lane >> 4;

    // A tile: [3 rows][66 cols][APAD] fp16 = 28512 B
    __shared__ __align__(16) unsigned short smem[3 * 66 * APAD];

    const int boff = g * 2048 + (w * 32 + p0) * 8;

    half8 bp[XNB][2];
    #pragma unroll
    for (int sc = 0; sc < XPF; ++sc) BLOAD(sc, sc)

    // stage A tile rows y-1..y+1
    const float* __restrict__ xt = x + (size_t)(n * TT + t) * 4096 * 64;
    for (int idx = tid; idx < 3 * 66 * 8; idx += 512) {
        const int cg  = idx & 7;
        const int col = (idx >> 3) % 66;
        const int r   = (idx >> 3) / 66;
        const int gy = y + r - 1;
        const int gx = col - 1;
        const bool ok = ((unsigned)gy < 64u) && ((unsigned)gx < 64u);
        float4 v0 = make_float4(0.f, 0.f, 0.f, 0.f), v1 = v0;
        if (ok) {
            const float* p = xt + (size_t)(gy * 64 + gx) * 64 + cg * 8;
            v0 = *(const float4*)p;
            v1 = *(const float4*)(p + 4);
        }
        __align__(16) unsigned short os[8];
        os[0] = f2h(v0.x); os[1] = f2h(v0.y); os[2] = f2h(v0.z); os[3] = f2h(v0.w);
        os[4] = f2h(v1.x); os[5] = f2h(v1.y); os[6] = f2h(v1.z); os[7] = f2h(v1.w);
        *(uint4*)&smem[(r * 66 + col) * APAD + cg * 8] = *(const uint4*)os;
    }
    __syncthreads();

    const unsigned short* abase = smem + p0 * APAD + g * 8;

    // K-loop: 18 chunks (Wx), 4 m-frags (64 px), B from regs
    f32x4 acc[4][2] = {};
    #pragma unroll
    for (int sub = 0; sub < 18; ++sub) {
        if (sub + XPF < 18) BLOAD((sub + XPF) % XNB, sub + XPF)

        const int ky = sub / 6, kx = (sub / 2) % 3, cb = sub & 1;
        const half8 b0 = bp[sub % XNB][0];
        const half8 b1 = bp[sub % XNB][1];
        #pragma unroll
        for (int cq = 0; cq < 4; ++cq) {
            const half8 a = *(const half8*)(abase
                + (ky * 66 + cq * 16 + kx) * APAD + cb * 32);
            acc[cq][0] = __builtin_amdgcn_mfma_f32_16x16x32_f16(a, b0, acc[cq][0], 0, 0, 0);
            acc[cq][1] = __builtin_amdgcn_mfma_f32_16x16x32_f16(a, b1, acc[cq][1], 0, 0, 0);
        }
    }

    // packed xg store: 2 records (xh) of 32 B per lane; cq = xh*2 + mfc
    const float bv0 = bias[w * 32 + p0];
    const float bv1 = bias[w * 32 + 16 + p0];
    #pragma unroll
    for (int xh2 = 0; xh2 < 2; ++xh2) {
        unsigned short os[16];
        #pragma unroll
        for (int mfc = 0; mfc < 2; ++mfc)
            #pragma unroll
            for (int nf = 0; nf < 2; ++nf)
                #pragma unroll
                for (int j = 0; j < 4; ++j)
                    os[mfc * 8 + nf * 4 + j] =
                        f2h(acc[xh2 * 2 + mfc][nf][j] + (nf ? bv1 : bv0));
        const size_t vi = ((((size_t)(n * TT + t) * 64 + y) * 2 + xh2) * 8 + w) * 64 + lane;
        unsigned short* dst = xg + vi * 16;
        *(uint4*)dst       = *(uint4*)&os[0];
        *(uint4*)(dst + 8) = *(uint4*)&os[8];
    }
}

// Per-timestep xg-path kernel: 16-px blocks, grid 512 -> 2 blocks/CU (16 waves)
// Block = (n,y,xq): 16 px x 256 ch, 8 waves; wave w owns ch [w*32, w*32+32).
__global__ __launch_bounds__(512) void convstep16_kernel(
    const unsigned short* __restrict__ hb,
    const unsigned short* __restrict__ Wc,
    const unsigned short* __restrict__ xg,
    float* __restrict__ cbuf,
    unsigned short* __restrict__ ho,
    const float* __restrict__ bn,
    float* __restrict__ out,
    const int t)
{
    const int bid0 = blockIdx.x;
    const int bid = (bid0 & 7) * 64 + (bid0 >> 3);   // bijective XCD swizzle (512=8*64)
    const int xq = bid & 3;          // 16-col quarter
    const int y  = (bid >> 2) & 63;
    const int n  = bid >> 8;
    const int tid = threadIdx.x;
    const int lane = tid & 63;
    const int w = tid >> 6;
    const int p0 = lane & 15;
    const int g  = lane >> 4;

    // A: [3][18][APAD] fp16 = 7776 B; overlaid by gbuf [4][16][68] f32 = 17408 B
    __shared__ __align__(16) unsigned short smem[8704];

    // xg: one 16B half-record per lane (mf = xq&1 of the 32-px producer record)
    unsigned short xs[8];
    {
        const size_t vi = ((((size_t)(n * TT + t) * 64 + y) * 2 + (xq >> 1)) * 8 + w) * 64 + lane;
        *(uint4*)&xs[0] = *(const uint4*)(xg + vi * 16 + (xq & 1) * 8);
    }

    // B prologue (Wh chunks 18..): 18 % NB == 0, slots 0..PF-1
    const int boff = g * 2048 + (w * 32 + p0) * 8;
    half8 bp[NB][2];
    #pragma unroll
    for (int sc = 0; sc < PF; ++sc) BLOAD((18 + sc) % NB, 18 + sc)

    // stage h tile: 3 rows x 18 cols
    const size_t hbase = (size_t)n * 4096 * 64;
    for (int idx = tid; idx < 3 * 18 * 8; idx += 512) {
        const int cg  = idx & 7;
        const int col = (idx >> 3) % 18;
        const int r   = (idx >> 3) / 18;
        const int gy = y + r - 1;
        const int gx = xq * 16 + col - 1;
        uint4 v = make_uint4(0u, 0u, 0u, 0u);
        if (((unsigned)gy < 64u) && ((unsigned)gx < 64u))
            v = *(const uint4*)(hb + hbase + (size_t)(gy * 64 + gx) * 64 + cg * 8);
        *(uint4*)&smem[(r * 18 + col) * APAD + cg * 8] = v;
    }
    __syncthreads();

    // K-loop: 18 chunks (Wh); 1 A-read + 2 MFMA per sub
    const unsigned short* abase = smem + p0 * APAD + g * 8;
    f32x4 acc[2] = {};
    #pragma unroll
    for (int sub = 0; sub < 18; ++sub) {
        const int ci = 18 + sub;
        if (ci + PF <= 35) BLOAD((ci + PF) % NB, ci + PF)

        const int ky = sub / 6, kx = (sub / 2) % 3, cb = sub & 1;
        const half8 b0 = bp[ci % NB][0];
        const half8 b1 = bp[ci % NB][1];
        const half8 a = *(const half8*)(abase + (ky * 18 + kx) * APAD + cb * 32);
        acc[0] = __builtin_amdgcn_mfma_f32_16x16x32_f16(a, b0, acc[0], 0, 0, 0);
        acc[1] = __builtin_amdgcn_mfma_f32_16x16x32_f16(a, b1, acc[1], 0, 0, 0);
    }

    // gates -> gbuf (overlay A region)
    __syncthreads();
    float* gbuf = (float*)smem;            // [4][16][68] f32
    const int gate = w >> 1;
    const int chalf = (w & 1) * 32;
    #pragma unroll
    for (int nf = 0; nf < 2; ++nf)
        #pragma unroll
        for (int j = 0; j < 4; ++j) {
            float v = acc[nf][j] + h2f(xs[nf * 4 + j]);
            v = (gate == 2) ? tanhf(v) : hsig(v);   // gate order i,f,g,o
            const int px = g * 4 + j;
            gbuf[(gate * 16 + px) * 68 + chalf + nf * 16 + p0] = v;
        }
    __syncthreads();

    // state update + BN output: thread -> (px = tid>>5, 2 channels)
    const int p  = tid >> 5;
    const int c2 = (tid & 31) * 2;
    const float2 iv = *(const float2*)&gbuf[(0 * 16 + p) * 68 + c2];
    const float2 fv = *(const float2*)&gbuf[(1 * 16 + p) * 68 + c2];
    const float2 gv = *(const float2*)&gbuf[(2 * 16 + p) * 68 + c2];
    const float2 ov = *(const float2*)&gbuf[(3 * 16 + p) * 68 + c2];
    const size_t sb = ((size_t)((n * 64 + y) * 64 + xq * 16 + p)) * 64 + c2;
    const float2 cold = *(const float2*)&cbuf[sb];
    const float2 scv  = *(const float2*)&bn[c2];
    const float2 shv  = *(const float2*)&bn[64 + c2];

    const float cn0 = fv.x * cold.x + iv.x * gv.x;
    const float cn1 = fv.y * cold.y + iv.y * gv.y;
    const float hn0 = ov.x * tanhf(cn0);
    const float hn1 = ov.y * tanhf(cn1);
    *(float2*)&cbuf[sb] = make_float2(cn0, cn1);
    const unsigned int hh = (unsigned int)f2h(hn0) | ((unsigned int)f2h(hn1) << 16);
    *(unsigned int*)&ho[sb] = hh;
    const size_t ob = ((size_t)((n * TT + t) * 4096 + y * 64 + xq * 16 + p)) * 64 + c2;
    *(float2*)&out[ob] = make_float2(hn0 * scv.x + shv.x, hn1 * scv.y + shv.y);
}

// Fallback fused per-step kernel (ws too small for xg): round-11 proven path.
template<int FUSED>
__global__ __launch_bounds__(512) void convstep_kernel(
    const float* __restrict__ x,
    const unsigned short* __restrict__ hb,
    const unsigned short* __restrict__ Wc,
    const float* __restrict__ bias,
    const unsigned short* __restrict__ xg,
    float* __restrict__ cbuf,
    unsigned short* __restrict__ ho,
    const float* __restrict__ bn,
    float* __restrict__ out,
    const int t)
{
    const int bid0 = blockIdx.x;
    const int bid = (bid0 & 7) * 32 + (bid0 >> 3);
    const int xh = bid & 1;
    const int y  = (bid >> 1) & 63;
    const int n  = bid >> 7;
    const int tid = threadIdx.x;
    const int lane = tid & 63;
    const int w = tid >> 6;
    const int p0 = lane & 15;
    const int g  = lane >> 4;

    constexpr int SMEM_SHORTS = FUSED ? (2 * A_TILE) : 17408;
    __shared__ __align__(16) unsigned short smem[SMEM_SHORTS];

    const int boff = g * 2048 + (w * 32 + p0) * 8;

    unsigned short xs[16];
    if (!FUSED) {
        const size_t vi = ((((size_t)(n * TT + t) * 64 + y) * 2 + xh) * 8 + w) * 64 + lane;
        const uint4* xp = (const uint4*)(xg + vi * 16);
        *(uint4*)&xs[0] = xp[0];
        *(uint4*)&xs[8] = xp[1];
    }

    constexpr int C0 = FUSED ? 0 : 18;
    half8 bp[NB][2];
    #pragma unroll
    for (int sc = 0; sc < PF; ++sc) BLOAD((C0 + sc) % NB, C0 + sc)

    constexpr int NTILE = FUSED ? 2 : 1;
    const float* __restrict__ xt = x + (size_t)(n * TT + t) * 4096 * 64;
    const size_t hbase = (size_t)n * 4096 * 64;
    for (int idx = tid; idx < NTILE * 3 * 34 * 8; idx += 512) {
        const int cg  = idx & 7;
        const int col = (idx >> 3) % 34;
        const int i3  = (idx >> 3) / 34;
        const int r   = i3 % 3;
        const int src = i3 / 3;
        const int gy = y + r - 1;
        const int gx = xh * 32 + col - 1;
        const bool ok = ((unsigned)gy < 64u) && ((unsigned)gx < 64u);
        const int ebase = (r * 34 + col) * APAD + cg * 8;
        if (FUSED && src == 0) {
            float4 v0 = make_float4(0.f, 0.f, 0.f, 0.f), v1 = v0;
            if (ok) {
                const float* p = xt + (size_t)(gy * 64 + gx) * 64 + cg * 8;
                v0 = *(const float4*)p;
                v1 = *(const float4*)(p + 4);
            }
            __align__(16) unsigned short os[8];
            os[0] = f2h(v0.x); os[1] = f2h(v0.y); os[2] = f2h(v0.z); os[3] = f2h(v0.w);
            os[4] = f2h(v1.x); os[5] = f2h(v1.y); os[6] = f2h(v1.z); os[7] = f2h(v1.w);
            *(uint4*)&smem[ebase] = *(const uint4*)os;
        } else {
            uint4 v = make_uint4(0u, 0u, 0u, 0u);
            if (ok) v = *(const uint4*)(hb + hbase + (size_t)(gy * 64 + gx) * 64 + cg * 8);
            *(uint4*)&smem[(FUSED ? A_TILE : 0) + ebase] = v;
        }
    }
    __syncthreads();

    const unsigned short* abase = smem + p0 * APAD + g * 8;

    f32x4 acc[2][2] = {};
    if (FUSED) {
        conv_pass18<0, 35, 0>(Wc, boff, bp, abase, acc);
        conv_pass18<18, 35, A_TILE>(Wc, boff, bp, abase, acc);
    } else {
        conv_pass18<18, 35, 0>(Wc, boff, bp, abase, acc);
    }

    __syncthreads();
    float* gbuf = (float*)smem;
    const int gate = w >> 1;
    const int chalf = (w & 1) * 32;

    float bv[2];
    bv[0] = bias[w * 32 + p0];
    bv[1] = bias[w * 32 + 16 + p0];

    #pragma unroll
    for (int mf = 0; mf < 2; ++mf)
        #pragma unroll
        for (int nf = 0; nf < 2; ++nf)
            #pragma unroll
            for (int j = 0; j < 4; ++j) {
                float v = acc[mf][nf][j] + (FUSED ? bv[nf] : h2f(xs[mf * 8 + nf * 4 + j]));
                v = (gate == 2) ? tanhf(v) : hsig(v);
                const int px = mf * 16 + g * 4 + j;
                gbuf[(gate * 32 + px) * 68 + chalf + nf * 16 + p0] = v;
            }
    __syncthreads();

    const int p  = tid >> 4;
    const int c4 = (tid & 15) * 4;
    const float4 iv = *(const float4*)&gbuf[(0 * 32 + p) * 68 + c4];
    const float4 fv = *(const float4*)&gbuf[(1 * 32 + p) * 68 + c4];
    const float4 gv = *(const float4*)&gbuf[(2 * 32 + p) * 68 + c4];
    const float4 ov = *(const float4*)&gbuf[(3 * 32 + p) * 68 + c4];
    const size_t sb = ((size_t)((n * 64 + y) * 64 + xh * 32 + p)) * 64 + c4;
    const float4 cold = *(const float4*)&cbuf[sb];
    const float4 scv  = *(const float4*)&bn[c4];
    const float4 shv  = *(const float4*)&bn[64 + c4];

    const float ivv[4] = {iv.x, iv.y, iv.z, iv.w};
    const float fvv[4] = {fv.x, fv.y, fv.z, fv.w};
    const float gvv[4] = {gv.x, gv.y, gv.z, gv.w};
    const float ovv[4] = {ov.x, ov.y, ov.z, ov.w};
    const float cov[4] = {cold.x, cold.y, cold.z, cold.w};
    const float scc[4] = {scv.x, scv.y, scv.z, scv.w};
    const float shh[4] = {shv.x, shv.y, shv.z, shv.w};

    float cnew[4], obuf[4];
    us4 hh;
    unsigned short* hhp = (unsigned short*)&hh;
    #pragma unroll
    for (int j = 0; j < 4; ++j) {
        const float cn = fvv[j] * cov[j] + ivv[j] * gvv[j];
        const float hn = ovv[j] * tanhf(cn);
        cnew[j] = cn;
        hhp[j] = f2h(hn);
        obuf[j] = hn * scc[j] + shh[j];
    }
    *(float4*)&cbuf[sb] = *(float4*)&cnew[0];
    *(us4*)&ho[sb]      = hh;
    const size_t ob = ((size_t)((n * TT + t) * 4096 + y * 64 + xh * 32 + p)) * 64 + c4;
    *(float4*)&out[ob] = *(float4*)&obuf[0];
}

extern "C" void kernel_launch(void* const* d_in, const int* in_sizes, int n_in,
                              void* d_out, int out_size, void* d_ws, size_t ws_size,
                              hipStream_t stream) {
    const float* x     = (const float*)d_in[0];
    const float* Wx    = (const float*)d_in[1];
    const float* Wh    = (const float*)d_in[2];
    const float* b     = (const float*)d_in[3];
    const float* gamma = (const float*)d_in[4];
    const float* beta  = (const float*)d_in[5];
    const float* mean  = (const float*)d_in[6];
    const float* var   = (const float*)d_in[7];
    float* out = (float*)d_out;
    char* ws = (char*)d_ws;

    unsigned short* Wc   = (unsigned short*)(ws);            // 589,824 B
    float*          bn   = (float*)(ws + 589824);            // 512 B
    unsigned short* hA   = (unsigned short*)(ws + 590336);   // 1 MB fp16
    float*          cbuf = (float*)(ws + 1638912);           // 2 MB fp32
    unsigned short* hB   = (unsigned short*)(ws + 3736064);  // 1 MB fp16
    unsigned short* xg   = (unsigned short*)(ws + 4784640);  // 67,108,864 B
    const size_t NEED = 4784640ull + 67108864ull;            // 71,893,504 B

    hipMemsetAsync(ws + 590336, 0, 3145728, stream);         // h0 + c0 = 0
    prep_kernel<<<1153, 256, 0, stream>>>(Wx, Wh, gamma, beta, mean, var, Wc, bn);

    if (ws_size >= NEED) {
        xconv_kernel<<<2048, 512, 0, stream>>>(x, Wc, b, xg);
        for (int t = 0; t < TT; ++t) {
            const bool even = (t & 1) == 0;
            convstep16_kernel<<<512, 512, 0, stream>>>(
                even ? hA : hB, Wc, xg, cbuf, even ? hB : hA, bn, out, t);
        }
    } else {
        for (int t = 0; t < TT; ++t) {
            const bool even = (t & 1) == 0;
            convstep_kernel<1><<<256, 512, 0, stream>>>(
                x, even ? hA : hB, Wc, b, xg, cbuf, even ? hB : hA, bn, out, t);
        }
    }
}

// Round 16
// 218.896 us; speedup vs baseline: 1.0000x; 1.0000x over previous
//
#include <hip/hip_runtime.h>
#include <cstddef>

typedef __attribute__((ext_vector_type(8))) _Float16 half8;
typedef __attribute__((ext_vector_type(4))) float f32x4;
typedef __attribute__((ext_vector_type(4))) unsigned short us4;

#define TT 16
#define APAD 72                 // shorts per (row,col) slot: 144 B
#define A_TILE (3*34*APAD)      // fallback-kernel tile: 7344 shorts
#define CHUNK  8192             // shorts per 16KB weight chunk
#define NB     6                // B reg-pipeline slots
#define PF     5                // prefetch distance (< NB)
#define XNB    4                // B reg-pipeline slots (xconv)
#define XPF    3                // xconv prefetch distance (< XNB)

__device__ __forceinline__ unsigned short f2h(float f) {
    return __builtin_bit_cast(unsigned short, (_Float16)f);
}
__device__ __forceinline__ float h2f(unsigned short u) {
    return (float)__builtin_bit_cast(_Float16, u);
}
__device__ __forceinline__ float hsig(float z) {
    return fminf(fmaxf(0.2f * z + 0.5f, 0.f), 1.f);
}

// Weight pack (fp16): Wc short idx i = (s*4 + kg)*2048 + n*8 + j, s in [0,36)
// s<18 -> Wx chunk sub=s ; s>=18 -> Wh chunk sub=s-18
__global__ __launch_bounds__(256) void prep_kernel(
    const float* __restrict__ Wx, const float* __restrict__ Wh,
    const float* __restrict__ gamma, const float* __restrict__ beta,
    const float* __restrict__ mean, const float* __restrict__ var,
    unsigned short* __restrict__ Wc, float* __restrict__ bn)
{
    if (blockIdx.x == 1152) {
        if (threadIdx.x < 64) {
            const int c = threadIdx.x;
            const float inv = gamma[c] * rsqrtf(var[c] + 1e-3f);
            bn[c] = inv;
            bn[64 + c] = beta[c] - mean[c] * inv;
        }
        return;
    }
    const int i = blockIdx.x * 256 + threadIdx.x;   // < 294912
    const int j  = i & 7;
    const int n  = (i >> 3) & 255;
    const int kg = (i >> 11) & 3;
    const int s  = i >> 13;            // 0..35
    const int sub = s % 18;
    const float* W = (s >= 18) ? Wh : Wx;
    const int k5 = sub * 32 + kg * 8 + j;
    const int c = k5 & 63, q = k5 >> 6;
    const int kx = q % 3, ky = q / 3;
    Wc[i] = f2h(W[(size_t)((ky * 3 + kx) * 64 + c) * 256 + n]);
}

// B-frag register loads: chunk ci, this lane's pair (nf=0 at boff, nf=1 at +128)
#define BLOAD(slot, ci) {                                                     \
    const unsigned short* _p = Wc + (size_t)(ci) * CHUNK + boff;              \
    bp[slot][0] = *(const half8*)_p;                                          \
    bp[slot][1] = *(const half8*)(_p + 128);                                  \
}

// 18-chunk conv pass (fallback fused kernel), B from reg pipeline.
template<int C0, int CLAST, int AOFF>
__device__ __forceinline__ void conv_pass18(
    const unsigned short* __restrict__ Wc, const int boff,
    half8 (&bp)[NB][2],
    const unsigned short* abase,
    f32x4 acc[2][2])
{
    #pragma unroll
    for (int sub = 0; sub < 18; ++sub) {
        const int ci = C0 + sub;
        if (ci + PF <= CLAST) BLOAD((ci + PF) % NB, ci + PF)

        const int ky = sub / 6, kx = (sub / 2) % 3, cb = sub & 1;
        const half8 b0 = bp[ci % NB][0];
        const half8 b1 = bp[ci % NB][1];
        const unsigned short* at = abase + AOFF + (ky * 34 + kx) * APAD + cb * 32;
        const half8 a0 = *(const half8*)(at);
        const half8 a1 = *(const half8*)(at + 16 * APAD);
        acc[0][0] = __builtin_amdgcn_mfma_f32_16x16x32_f16(a0, b0, acc[0][0], 0, 0, 0);
        acc[0][1] = __builtin_amdgcn_mfma_f32_16x16x32_f16(a0, b1, acc[0][1], 0, 0, 0);
        acc[1][0] = __builtin_amdgcn_mfma_f32_16x16x32_f16(a1, b0, acc[1][0], 0, 0, 0);
        acc[1][1] = __builtin_amdgcn_mfma_f32_16x16x32_f16(a1, b1, acc[1][1], 0, 0, 0);
    }
}

// Hoisted x-conv, 1 row/block (round-13 proven version, linear APAD layout).
// record vi = ((((n*16+t)*64+y)*2+xh)*8+w)*64+lane -> 16 shorts [mfc][nf][j].
__global__ __launch_bounds__(512) void xconv_kernel(
    const float* __restrict__ x,
    const unsigned short* __restrict__ Wc,
    const float* __restrict__ bias,
    unsigned short* __restrict__ xg)
{
    const int bid0 = blockIdx.x;
    const int bid = (bid0 & 7) * 256 + (bid0 >> 3);  // bijective XCD swizzle (2048=8*256)
    const int y = bid & 63;
    const int t = (bid >> 6) & 15;
    const int n = bid >> 10;
    const int tid = threadIdx.x, lane = tid & 63, w = tid >> 6;
    const int p0 = lane & 15, g = lane >> 4;

    // A tile: [3 rows][66 cols][APAD] fp16 = 28512 B
    __shared__ __align__(16) unsigned short smem[3 * 66 * APAD];

    const int boff = g * 2048 + (w * 32 + p0) * 8;

    half8 bp[XNB][2];
    #pragma unroll
    for (int sc = 0; sc < XPF; ++sc) BLOAD(sc, sc)

    // stage A tile rows y-1..y+1
    const float* __restrict__ xt = x + (size_t)(n * TT + t) * 4096 * 64;
    for (int idx = tid; idx < 3 * 66 * 8; idx += 512) {
        const int cg  = idx & 7;
        const int col = (idx >> 3) % 66;
        const int r   = (idx >> 3) / 66;
        const int gy = y + r - 1;
        const int gx = col - 1;
        const bool ok = ((unsigned)gy < 64u) && ((unsigned)gx < 64u);
        float4 v0 = make_float4(0.f, 0.f, 0.f, 0.f), v1 = v0;
        if (ok) {
            const float* p = xt + (size_t)(gy * 64 + gx) * 64 + cg * 8;
            v0 = *(const float4*)p;
            v1 = *(const float4*)(p + 4);
        }
        __align__(16) unsigned short os[8];
        os[0] = f2h(v0.x); os[1] = f2h(v0.y); os[2] = f2h(v0.z); os[3] = f2h(v0.w);
        os[4] = f2h(v1.x); os[5] = f2h(v1.y); os[6] = f2h(v1.z); os[7] = f2h(v1.w);
        *(uint4*)&smem[(r * 66 + col) * APAD + cg * 8] = *(const uint4*)os;
    }
    __syncthreads();

    const unsigned short* abase = smem + p0 * APAD + g * 8;

    // K-loop: 18 chunks (Wx), 4 m-frags (64 px), B from regs
    f32x4 acc[4][2] = {};
    #pragma unroll
    for (int sub = 0; sub < 18; ++sub) {
        if (sub + XPF < 18) BLOAD((sub + XPF) % XNB, sub + XPF)

        const int ky = sub / 6, kx = (sub / 2) % 3, cb = sub & 1;
        const half8 b0 = bp[sub % XNB][0];
        const half8 b1 = bp[sub % XNB][1];
        #pragma unroll
        for (int cq = 0; cq < 4; ++cq) {
            const half8 a = *(const half8*)(abase
                + (ky * 66 + cq * 16 + kx) * APAD + cb * 32);
            acc[cq][0] = __builtin_amdgcn_mfma_f32_16x16x32_f16(a, b0, acc[cq][0], 0, 0, 0);
            acc[cq][1] = __builtin_amdgcn_mfma_f32_16x16x32_f16(a, b1, acc[cq][1], 0, 0, 0);
        }
    }

    // packed xg store: 2 records (xh) of 32 B per lane; cq = xh*2 + mfc
    const float bv0 = bias[w * 32 + p0];
    const float bv1 = bias[w * 32 + 16 + p0];
    #pragma unroll
    for (int xh2 = 0; xh2 < 2; ++xh2) {
        unsigned short os[16];
        #pragma unroll
        for (int mfc = 0; mfc < 2; ++mfc)
            #pragma unroll
            for (int nf = 0; nf < 2; ++nf)
                #pragma unroll
                for (int j = 0; j < 4; ++j)
                    os[mfc * 8 + nf * 4 + j] =
                        f2h(acc[xh2 * 2 + mfc][nf][j] + (nf ? bv1 : bv0));
        const size_t vi = ((((size_t)(n * TT + t) * 64 + y) * 2 + xh2) * 8 + w) * 64 + lane;
        unsigned short* dst = xg + vi * 16;
        *(uint4*)dst       = *(uint4*)&os[0];
        *(uint4*)(dst + 8) = *(uint4*)&os[8];
    }
}

// Per-timestep xg-path kernel: 16-px blocks, grid 512 -> 2 blocks/CU (16 waves)
// Block = (n,y,xq): 16 px x 256 ch, 8 waves; wave w owns ch [w*32, w*32+32).
__global__ __launch_bounds__(512) void convstep16_kernel(
    const unsigned short* __restrict__ hb,
    const unsigned short* __restrict__ Wc,
    const unsigned short* __restrict__ xg,
    float* __restrict__ cbuf,
    unsigned short* __restrict__ ho,
    const float* __restrict__ bn,
    float* __restrict__ out,
    const int t)
{
    const int bid0 = blockIdx.x;
    const int bid = (bid0 & 7) * 64 + (bid0 >> 3);   // bijective XCD swizzle (512=8*64)
    const int xq = bid & 3;          // 16-col quarter
    const int y  = (bid >> 2) & 63;
    const int n  = bid >> 8;
    const int tid = threadIdx.x;
    const int lane = tid & 63;
    const int w = tid >> 6;
    const int p0 = lane & 15;
    const int g  = lane >> 4;

    // A: [3][18][APAD] fp16 = 7776 B; overlaid by gbuf [4][16][68] f32 = 17408 B
    __shared__ __align__(16) unsigned short smem[8704];

    // xg: one 16B half-record per lane (mf = xq&1 of the 32-px producer record)
    unsigned short xs[8];
    {
        const size_t vi = ((((size_t)(n * TT + t) * 64 + y) * 2 + (xq >> 1)) * 8 + w) * 64 + lane;
        *(uint4*)&xs[0] = *(const uint4*)(xg + vi * 16 + (xq & 1) * 8);
    }

    // B prologue (Wh chunks 18..): 18 % NB == 0, slots 0..PF-1
    const int boff = g * 2048 + (w * 32 + p0) * 8;
    half8 bp[NB][2];
    #pragma unroll
    for (int sc = 0; sc < PF; ++sc) BLOAD((18 + sc) % NB, 18 + sc)

    // stage h tile: 3 rows x 18 cols
    const size_t hbase = (size_t)n * 4096 * 64;
    for (int idx = tid; idx < 3 * 18 * 8; idx += 512) {
        const int cg  = idx & 7;
        const int col = (idx >> 3) % 18;
        const int r   = (idx >> 3) / 18;
        const int gy = y + r - 1;
        const int gx = xq * 16 + col - 1;
        uint4 v = make_uint4(0u, 0u, 0u, 0u);
        if (((unsigned)gy < 64u) && ((unsigned)gx < 64u))
            v = *(const uint4*)(hb + hbase + (size_t)(gy * 64 + gx) * 64 + cg * 8);
        *(uint4*)&smem[(r * 18 + col) * APAD + cg * 8] = v;
    }
    __syncthreads();

    // K-loop: 18 chunks (Wh); 1 A-read + 2 MFMA per sub
    const unsigned short* abase = smem + p0 * APAD + g * 8;
    f32x4 acc[2] = {};
    #pragma unroll
    for (int sub = 0; sub < 18; ++sub) {
        const int ci = 18 + sub;
        if (ci + PF <= 35) BLOAD((ci + PF) % NB, ci + PF)

        const int ky = sub / 6, kx = (sub / 2) % 3, cb = sub & 1;
        const half8 b0 = bp[ci % NB][0];
        const half8 b1 = bp[ci % NB][1];
        const half8 a = *(const half8*)(abase + (ky * 18 + kx) * APAD + cb * 32);
        acc[0] = __builtin_amdgcn_mfma_f32_16x16x32_f16(a, b0, acc[0], 0, 0, 0);
        acc[1] = __builtin_amdgcn_mfma_f32_16x16x32_f16(a, b1, acc[1], 0, 0, 0);
    }

    // gates -> gbuf (overlay A region)
    __syncthreads();
    float* gbuf = (float*)smem;            // [4][16][68] f32
    const int gate = w >> 1;
    const int chalf = (w & 1) * 32;
    #pragma unroll
    for (int nf = 0; nf < 2; ++nf)
        #pragma unroll
        for (int j = 0; j < 4; ++j) {
            float v = acc[nf][j] + h2f(xs[nf * 4 + j]);
            v = (gate == 2) ? tanhf(v) : hsig(v);   // gate order i,f,g,o
            const int px = g * 4 + j;
            gbuf[(gate * 16 + px) * 68 + chalf + nf * 16 + p0] = v;
        }
    __syncthreads();

    // state update + BN output: thread -> (px = tid>>5, 2 channels)
    const int p  = tid >> 5;
    const int c2 = (tid & 31) * 2;
    const float2 iv = *(const float2*)&gbuf[(0 * 16 + p) * 68 + c2];
    const float2 fv = *(const float2*)&gbuf[(1 * 16 + p) * 68 + c2];
    const float2 gv = *(const float2*)&gbuf[(2 * 16 + p) * 68 + c2];
    const float2 ov = *(const float2*)&gbuf[(3 * 16 + p) * 68 + c2];
    const size_t sb = ((size_t)((n * 64 + y) * 64 + xq * 16 + p)) * 64 + c2;
    const float2 cold = *(const float2*)&cbuf[sb];
    const float2 scv  = *(const float2*)&bn[c2];
    const float2 shv  = *(const float2*)&bn[64 + c2];

    const float cn0 = fv.x * cold.x + iv.x * gv.x;
    const float cn1 = fv.y * cold.y + iv.y * gv.y;
    const float hn0 = ov.x * tanhf(cn0);
    const float hn1 = ov.y * tanhf(cn1);
    *(float2*)&cbuf[sb] = make_float2(cn0, cn1);
    const unsigned int hh = (unsigned int)f2h(hn0) | ((unsigned int)f2h(hn1) << 16);
    *(unsigned int*)&ho[sb] = hh;
    const size_t ob = ((size_t)((n * TT + t) * 4096 + y * 64 + xq * 16 + p)) * 64 + c2;
    *(float2*)&out[ob] = make_float2(hn0 * scv.x + shv.x, hn1 * scv.y + shv.y);
}

// Fallback fused per-step kernel (ws too small for xg): round-11 proven path.
template<int FUSED>
__global__ __launch_bounds__(512) void convstep_kernel(
    const float* __restrict__ x,
    const unsigned short* __restrict__ hb,
    const unsigned short* __restrict__ Wc,
    const float* __restrict__ bias,
    const unsigned short* __restrict__ xg,
    float* __restrict__ cbuf,
    unsigned short* __restrict__ ho,
    const float* __restrict__ bn,
    float* __restrict__ out,
    const int t)
{
    const int bid0 = blockIdx.x;
    const int bid = (bid0 & 7) * 32 + (bid0 >> 3);
    const int xh = bid & 1;
    const int y  = (bid >> 1) & 63;
    const int n  = bid >> 7;
    const int tid = threadIdx.x;
    const int lane = tid & 63;
    const int w = tid >> 6;
    const int p0 = lane & 15;
    const int g  = lane >> 4;

    constexpr int SMEM_SHORTS = FUSED ? (2 * A_TILE) : 17408;
    __shared__ __align__(16) unsigned short smem[SMEM_SHORTS];

    const int boff = g * 2048 + (w * 32 + p0) * 8;

    unsigned short xs[16];
    if (!FUSED) {
        const size_t vi = ((((size_t)(n * TT + t) * 64 + y) * 2 + xh) * 8 + w) * 64 + lane;
        const uint4* xp = (const uint4*)(xg + vi * 16);
        *(uint4*)&xs[0] = xp[0];
        *(uint4*)&xs[8] = xp[1];
    }

    constexpr int C0 = FUSED ? 0 : 18;
    half8 bp[NB][2];
    #pragma unroll
    for (int sc = 0; sc < PF; ++sc) BLOAD((C0 + sc) % NB, C0 + sc)

    constexpr int NTILE = FUSED ? 2 : 1;
    const float* __restrict__ xt = x + (size_t)(n * TT + t) * 4096 * 64;
    const size_t hbase = (size_t)n * 4096 * 64;
    for (int idx = tid; idx < NTILE * 3 * 34 * 8; idx += 512) {
        const int cg  = idx & 7;
        const int col = (idx >> 3) % 34;
        const int i3  = (idx >> 3) / 34;
        const int r   = i3 % 3;
        const int src = i3 / 3;
        const int gy = y + r - 1;
        const int gx = xh * 32 + col - 1;
        const bool ok = ((unsigned)gy < 64u) && ((unsigned)gx < 64u);
        const int ebase = (r * 34 + col) * APAD + cg * 8;
        if (FUSED && src == 0) {
            float4 v0 = make_float4(0.f, 0.f, 0.f, 0.f), v1 = v0;
            if (ok) {
                const float* p = xt + (size_t)(gy * 64 + gx) * 64 + cg * 8;
                v0 = *(const float4*)p;
                v1 = *(const float4*)(p + 4);
            }
            __align__(16) unsigned short os[8];
            os[0] = f2h(v0.x); os[1] = f2h(v0.y); os[2] = f2h(v0.z); os[3] = f2h(v0.w);
            os[4] = f2h(v1.x); os[5] = f2h(v1.y); os[6] = f2h(v1.z); os[7] = f2h(v1.w);
            *(uint4*)&smem[ebase] = *(const uint4*)os;
        } else {
            uint4 v = make_uint4(0u, 0u, 0u, 0u);
            if (ok) v = *(const uint4*)(hb + hbase + (size_t)(gy * 64 + gx) * 64 + cg * 8);
            *(uint4*)&smem[(FUSED ? A_TILE : 0) + ebase] = v;
        }
    }
    __syncthreads();

    const unsigned short* abase = smem + p0 * APAD + g * 8;

    f32x4 acc[2][2] = {};
    if (FUSED) {
        conv_pass18<0, 35, 0>(Wc, boff, bp, abase, acc);
        conv_pass18<18, 35, A_TILE>(Wc, boff, bp, abase, acc);
    } else {
        conv_pass18<18, 35, 0>(Wc, boff, bp, abase, acc);
    }

    __syncthreads();
    float* gbuf = (float*)smem;
    const int gate = w >> 1;
    const int chalf = (w & 1) * 32;

    float bv[2];
    bv[0] = bias[w * 32 + p0];
    bv[1] = bias[w * 32 + 16 + p0];

    #pragma unroll
    for (int mf = 0; mf < 2; ++mf)
        #pragma unroll
        for (int nf = 0; nf < 2; ++nf)
            #pragma unroll
            for (int j = 0; j < 4; ++j) {
                float v = acc[mf][nf][j] + (FUSED ? bv[nf] : h2f(xs[mf * 8 + nf * 4 + j]));
                v = (gate == 2) ? tanhf(v) : hsig(v);
                const int px = mf * 16 + g * 4 + j;
                gbuf[(gate * 32 + px) * 68 + chalf + nf * 16 + p0] = v;
            }
    __syncthreads();

    const int p  = tid >> 4;
    const int c4 = (tid & 15) * 4;
    const float4 iv = *(const float4*)&gbuf[(0 * 32 + p) * 68 + c4];
    const float4 fv = *(const float4*)&gbuf[(1 * 32 + p) * 68 + c4];
    const float4 gv = *(const float4*)&gbuf[(2 * 32 + p) * 68 + c4];
    const float4 ov = *(const float4*)&gbuf[(3 * 32 + p) * 68 + c4];
    const size_t sb = ((size_t)((n * 64 + y) * 64 + xh * 32 + p)) * 64 + c4;
    const float4 cold = *(const float4*)&cbuf[sb];
    const float4 scv  = *(const float4*)&bn[c4];
    const float4 shv  = *(const float4*)&bn[64 + c4];

    const float ivv[4] = {iv.x, iv.y, iv.z, iv.w};
    const float fvv[4] = {fv.x, fv.y, fv.z, fv.w};
    const float gvv[4] = {gv.x, gv.y, gv.z, gv.w};
    const float ovv[4] = {ov.x, ov.y, ov.z, ov.w};
    const float cov[4] = {cold.x, cold.y, cold.z, cold.w};
    const float scc[4] = {scv.x, scv.y, scv.z, scv.w};
    const float shh[4] = {shv.x, shv.y, shv.z, shv.w};

    float cnew[4], obuf[4];
    us4 hh;
    unsigned short* hhp = (unsigned short*)&hh;
    #pragma unroll
    for (int j = 0; j < 4; ++j) {
        const float cn = fvv[j] * cov[j] + ivv[j] * gvv[j];
        const float hn = ovv[j] * tanhf(cn);
        cnew[j] = cn;
        hhp[j] = f2h(hn);
        obuf[j] = hn * scc[j] + shh[j];
    }
    *(float4*)&cbuf[sb] = *(float4*)&cnew[0];
    *(us4*)&ho[sb]      = hh;
    const size_t ob = ((size_t)((n * TT + t) * 4096 + y * 64 + xh * 32 + p)) * 64 + c4;
    *(float4*)&out[ob] = *(float4*)&obuf[0];
}

extern "C" void kernel_launch(void* const* d_in, const int* in_sizes, int n_in,
                              void* d_out, int out_size, void* d_ws, size_t ws_size,
                              hipStream_t stream) {
    const float* x     = (const float*)d_in[0];
    const float* Wx    = (const float*)d_in[1];
    const float* Wh    = (const float*)d_in[2];
    const float* b     = (const float*)d_in[3];
    const float* gamma = (const float*)d_in[4];
    const float* beta  = (const float*)d_in[5];
    const float* mean  = (const float*)d_in[6];
    const float* var   = (const float*)d_in[7];
    float* out = (float*)d_out;
    char* ws = (char*)d_ws;

    unsigned short* Wc   = (unsigned short*)(ws);            // 589,824 B
    float*          bn   = (float*)(ws + 589824);            // 512 B
    unsigned short* hA   = (unsigned short*)(ws + 590336);   // 1 MB fp16
    float*          cbuf = (float*)(ws + 1638912);           // 2 MB fp32
    unsigned short* hB   = (unsigned short*)(ws + 3736064);  // 1 MB fp16
    unsigned short* xg   = (unsigned short*)(ws + 4784640);  // 67,108,864 B
    const size_t NEED = 4784640ull + 67108864ull;            // 71,893,504 B

    hipMemsetAsync(ws + 590336, 0, 3145728, stream);         // h0 + c0 = 0
    prep_kernel<<<1153, 256, 0, stream>>>(Wx, Wh, gamma, beta, mean, var, Wc, bn);

    if (ws_size >= NEED) {
        xconv_kernel<<<2048, 512, 0, stream>>>(x, Wc, b, xg);
        for (int t = 0; t < TT; ++t) {
            const bool even = (t & 1) == 0;
            convstep16_kernel<<<512, 512, 0, stream>>>(
                even ? hA : hB, Wc, xg, cbuf, even ? hB : hA, bn, out, t);
        }
    } else {
        for (int t = 0; t < TT; ++t) {
            const bool even = (t & 1) == 0;
            convstep_kernel<1><<<256, 512, 0, stream>>>(
                x, even ? hA : hB, Wc, b, xg, cbuf, even ? hB : hA, bn, out, t);
        }
    }
}

// Round 17
// 198.970 us; speedup vs baseline: 1.1002x; 1.1001x over previous
//
#include <hip/hip_runtime.h>
#include <cstddef>

typedef __attribute__((ext_vector_type(8))) _Float16 half8;
typedef __attribute__((ext_vector_type(4))) float f32x4;
typedef __attribute__((ext_vector_type(4))) unsigned short us4;

#define TT 16
#define APAD 72                 // shorts per (row,col) slot: 144 B
#define A_TILE (3*34*APAD)      // step-kernel tile: 7344 shorts
#define CHUNK  8192             // shorts per 16KB weight chunk
#define NB     6                // B reg-pipeline slots
#define PF     5                // prefetch distance (< NB)
#define XNB    4                // B reg-pipeline slots (xconv)
#define XPF    3                // xconv prefetch distance (< XNB)

__device__ __forceinline__ unsigned short f2h(float f) {
    return __builtin_bit_cast(unsigned short, (_Float16)f);
}
__device__ __forceinline__ float h2f(unsigned short u) {
    return (float)__builtin_bit_cast(_Float16, u);
}
__device__ __forceinline__ float hsig(float z) {
    return fminf(fmaxf(0.2f * z + 0.5f, 0.f), 1.f);
}

// Weight pack (fp16): Wc short idx i = (s*4 + kg)*2048 + n*8 + j, s in [0,36)
// s<18 -> Wx chunk sub=s ; s>=18 -> Wh chunk sub=s-18
__global__ __launch_bounds__(256) void prep_kernel(
    const float* __restrict__ Wx, const float* __restrict__ Wh,
    const float* __restrict__ gamma, const float* __restrict__ beta,
    const float* __restrict__ mean, const float* __restrict__ var,
    unsigned short* __restrict__ Wc, float* __restrict__ bn)
{
    if (blockIdx.x == 1152) {
        if (threadIdx.x < 64) {
            const int c = threadIdx.x;
            const float inv = gamma[c] * rsqrtf(var[c] + 1e-3f);
            bn[c] = inv;
            bn[64 + c] = beta[c] - mean[c] * inv;
        }
        return;
    }
    const int i = blockIdx.x * 256 + threadIdx.x;   // < 294912
    const int j  = i & 7;
    const int n  = (i >> 3) & 255;
    const int kg = (i >> 11) & 3;
    const int s  = i >> 13;            // 0..35
    const int sub = s % 18;
    const float* W = (s >= 18) ? Wh : Wx;
    const int k5 = sub * 32 + kg * 8 + j;
    const int c = k5 & 63, q = k5 >> 6;
    const int kx = q % 3, ky = q / 3;
    Wc[i] = f2h(W[(size_t)((ky * 3 + kx) * 64 + c) * 256 + n]);
}

// B-frag register loads: chunk ci, this lane's pair (nf=0 at boff, nf=1 at +128)
#define BLOAD(slot, ci) {                                                     \
    const unsigned short* _p = Wc + (size_t)(ci) * CHUNK + boff;              \
    bp[slot][0] = *(const half8*)_p;                                          \
    bp[slot][1] = *(const half8*)(_p + 128);                                  \
}

// 18-chunk conv pass, B from reg pipeline.
template<int C0, int CLAST, int AOFF>
__device__ __forceinline__ void conv_pass18(
    const unsigned short* __restrict__ Wc, const int boff,
    half8 (&bp)[NB][2],
    const unsigned short* abase,
    f32x4 acc[2][2])
{
    #pragma unroll
    for (int sub = 0; sub < 18; ++sub) {
        const int ci = C0 + sub;
        if (ci + PF <= CLAST) BLOAD((ci + PF) % NB, ci + PF)

        const int ky = sub / 6, kx = (sub / 2) % 3, cb = sub & 1;
        const half8 b0 = bp[ci % NB][0];
        const half8 b1 = bp[ci % NB][1];
        const unsigned short* at = abase + AOFF + (ky * 34 + kx) * APAD + cb * 32;
        const half8 a0 = *(const half8*)(at);
        const half8 a1 = *(const half8*)(at + 16 * APAD);
        acc[0][0] = __builtin_amdgcn_mfma_f32_16x16x32_f16(a0, b0, acc[0][0], 0, 0, 0);
        acc[0][1] = __builtin_amdgcn_mfma_f32_16x16x32_f16(a0, b1, acc[0][1], 0, 0, 0);
        acc[1][0] = __builtin_amdgcn_mfma_f32_16x16x32_f16(a1, b0, acc[1][0], 0, 0, 0);
        acc[1][1] = __builtin_amdgcn_mfma_f32_16x16x32_f16(a1, b1, acc[1][1], 0, 0, 0);
    }
}

// Hoisted x-conv, 1 row/block (round-13 proven version, linear APAD layout).
// record vi = ((((n*16+t)*64+y)*2+xh)*8+w)*64+lane -> 16 shorts [mfc][nf][j].
__global__ __launch_bounds__(512) void xconv_kernel(
    const float* __restrict__ x,
    const unsigned short* __restrict__ Wc,
    const float* __restrict__ bias,
    unsigned short* __restrict__ xg)
{
    const int bid0 = blockIdx.x;
    const int bid = (bid0 & 7) * 256 + (bid0 >> 3);  // bijective XCD swizzle (2048=8*256)
    const int y = bid & 63;
    const int t = (bid >> 6) & 15;
    const int n = bid >> 10;
    const int tid = threadIdx.x, lane = tid & 63, w = tid >> 6;
    const int p0 = lane & 15, g = lane >> 4;

    // A tile: [3 rows][66 cols][APAD] fp16 = 28512 B
    __shared__ __align__(16) unsigned short smem[3 * 66 * APAD];

    const int boff = g * 2048 + (w * 32 + p0) * 8;

    half8 bp[XNB][2];
    #pragma unroll
    for (int sc = 0; sc < XPF; ++sc) BLOAD(sc, sc)

    // stage A tile rows y-1..y+1
    const float* __restrict__ xt = x + (size_t)(n * TT + t) * 4096 * 64;
    for (int idx = tid; idx < 3 * 66 * 8; idx += 512) {
        const int cg  = idx & 7;
        const int col = (idx >> 3) % 66;
        const int r   = (idx >> 3) / 66;
        const int gy = y + r - 1;
        const int gx = col - 1;
        const bool ok = ((unsigned)gy < 64u) && ((unsigned)gx < 64u);
        float4 v0 = make_float4(0.f, 0.f, 0.f, 0.f), v1 = v0;
        if (ok) {
            const float* p = xt + (size_t)(gy * 64 + gx) * 64 + cg * 8;
            v0 = *(const float4*)p;
            v1 = *(const float4*)(p + 4);
        }
        __align__(16) unsigned short os[8];
        os[0] = f2h(v0.x); os[1] = f2h(v0.y); os[2] = f2h(v0.z); os[3] = f2h(v0.w);
        os[4] = f2h(v1.x); os[5] = f2h(v1.y); os[6] = f2h(v1.z); os[7] = f2h(v1.w);
        *(uint4*)&smem[(r * 66 + col) * APAD + cg * 8] = *(const uint4*)os;
    }
    __syncthreads();

    const unsigned short* abase = smem + p0 * APAD + g * 8;

    // K-loop: 18 chunks (Wx), 4 m-frags (64 px), B from regs
    f32x4 acc[4][2] = {};
    #pragma unroll
    for (int sub = 0; sub < 18; ++sub) {
        if (sub + XPF < 18) BLOAD((sub + XPF) % XNB, sub + XPF)

        const int ky = sub / 6, kx = (sub / 2) % 3, cb = sub & 1;
        const half8 b0 = bp[sub % XNB][0];
        const half8 b1 = bp[sub % XNB][1];
        #pragma unroll
        for (int cq = 0; cq < 4; ++cq) {
            const half8 a = *(const half8*)(abase
                + (ky * 66 + cq * 16 + kx) * APAD + cb * 32);
            acc[cq][0] = __builtin_amdgcn_mfma_f32_16x16x32_f16(a, b0, acc[cq][0], 0, 0, 0);
            acc[cq][1] = __builtin_amdgcn_mfma_f32_16x16x32_f16(a, b1, acc[cq][1], 0, 0, 0);
        }
    }

    // packed xg store: 2 records (xh) of 32 B per lane; cq = xh*2 + mfc
    const float bv0 = bias[w * 32 + p0];
    const float bv1 = bias[w * 32 + 16 + p0];
    #pragma unroll
    for (int xh2 = 0; xh2 < 2; ++xh2) {
        unsigned short os[16];
        #pragma unroll
        for (int mfc = 0; mfc < 2; ++mfc)
            #pragma unroll
            for (int nf = 0; nf < 2; ++nf)
                #pragma unroll
                for (int j = 0; j < 4; ++j)
                    os[mfc * 8 + nf * 4 + j] =
                        f2h(acc[xh2 * 2 + mfc][nf][j] + (nf ? bv1 : bv0));
        const size_t vi = ((((size_t)(n * TT + t) * 64 + y) * 2 + xh2) * 8 + w) * 64 + lane;
        unsigned short* dst = xg + vi * 16;
        *(uint4*)dst       = *(uint4*)&os[0];
        *(uint4*)(dst + 8) = *(uint4*)&os[8];
    }
}

// Per-timestep kernel. FUSED=1: full x+h conv (ws fallback). FUSED=0: h-conv + xg,
// with t==0 fast path (h0=c0=0: skip staging/K-loop, cold=0 — logic proven in r12).
// Block = (n,y,xhalf): 32 px x 256 ch, 8 waves.
template<int FUSED>
__global__ __launch_bounds__(512) void convstep_kernel(
    const float* __restrict__ x,
    const unsigned short* __restrict__ hb,
    const unsigned short* __restrict__ Wc,
    const float* __restrict__ bias,
    const unsigned short* __restrict__ xg,
    float* __restrict__ cbuf,
    unsigned short* __restrict__ ho,
    const float* __restrict__ bn,
    float* __restrict__ out,
    const int t)
{
    const int bid0 = blockIdx.x;
    const int bid = (bid0 & 7) * 32 + (bid0 >> 3);   // bijective XCD swizzle
    const int xh = bid & 1;
    const int y  = (bid >> 1) & 63;
    const int n  = bid >> 7;
    const int tid = threadIdx.x;
    const int lane = tid & 63;
    const int w = tid >> 6;
    const int p0 = lane & 15;
    const int g  = lane >> 4;

    // smem: A tiles; overlaid by gate buffer [4][32][68] f32 = 34816 B after K-loop
    constexpr int SMEM_SHORTS = FUSED ? (2 * A_TILE) : 17408;   // FUSED0: 34816 B
    __shared__ __align__(16) unsigned short smem[SMEM_SHORTS];

    const int boff = g * 2048 + (w * 32 + p0) * 8;
    const bool do_h = FUSED || (t > 0);     // wave-uniform

    // packed xg prefetch: one 32B record per lane
    unsigned short xs[16];
    if (!FUSED) {
        const size_t vi = ((((size_t)(n * TT + t) * 64 + y) * 2 + xh) * 8 + w) * 64 + lane;
        const uint4* xp = (const uint4*)(xg + vi * 16);
        *(uint4*)&xs[0] = xp[0];
        *(uint4*)&xs[8] = xp[1];
    }

    f32x4 acc[2][2] = {};
    if (do_h) {
        // B prologue into regs (latency hides under A-staging)
        constexpr int C0 = FUSED ? 0 : 18;
        half8 bp[NB][2];
        #pragma unroll
        for (int sc = 0; sc < PF; ++sc) BLOAD((C0 + sc) % NB, C0 + sc)

        // ---- stage A tiles: FUSED: x(tile0) + h(tile1); else h(tile0) ----
        constexpr int NTILE = FUSED ? 2 : 1;
        const float* __restrict__ xt = x + (size_t)(n * TT + t) * 4096 * 64;
        const size_t hbase = (size_t)n * 4096 * 64;
        for (int idx = tid; idx < NTILE * 3 * 34 * 8; idx += 512) {
            const int cg  = idx & 7;
            const int col = (idx >> 3) % 34;
            const int i3  = (idx >> 3) / 34;
            const int r   = i3 % 3;
            const int src = i3 / 3;
            const int gy = y + r - 1;
            const int gx = xh * 32 + col - 1;
            const bool ok = ((unsigned)gy < 64u) && ((unsigned)gx < 64u);
            const int ebase = (r * 34 + col) * APAD + cg * 8;
            if (FUSED && src == 0) {
                float4 v0 = make_float4(0.f, 0.f, 0.f, 0.f), v1 = v0;
                if (ok) {
                    const float* p = xt + (size_t)(gy * 64 + gx) * 64 + cg * 8;
                    v0 = *(const float4*)p;
                    v1 = *(const float4*)(p + 4);
                }
                __align__(16) unsigned short os[8];
                os[0] = f2h(v0.x); os[1] = f2h(v0.y); os[2] = f2h(v0.z); os[3] = f2h(v0.w);
                os[4] = f2h(v1.x); os[5] = f2h(v1.y); os[6] = f2h(v1.z); os[7] = f2h(v1.w);
                *(uint4*)&smem[ebase] = *(const uint4*)os;
            } else {
                uint4 v = make_uint4(0u, 0u, 0u, 0u);
                if (ok) v = *(const uint4*)(hb + hbase + (size_t)(gy * 64 + gx) * 64 + cg * 8);
                *(uint4*)&smem[(FUSED ? A_TILE : 0) + ebase] = v;
            }
        }
        __syncthreads();

        // ---- K-loop (B from reg pipeline, compiler-managed waits) ----
        const unsigned short* abase = smem + p0 * APAD + g * 8;
        if (FUSED) {
            conv_pass18<0, 35, 0>(Wc, boff, bp, abase, acc);
            conv_pass18<18, 35, A_TILE>(Wc, boff, bp, abase, acc);
        } else {
            conv_pass18<18, 35, 0>(Wc, boff, bp, abase, acc);
        }
    }

    // ---- gates -> LDS gate buffer (overlay A region) ----
    __syncthreads();
    float* gbuf = (float*)smem;            // [4][32][68] f32 = 34816 B
    const int gate = w >> 1;
    const int chalf = (w & 1) * 32;

    float bv[2];
    bv[0] = bias[w * 32 + p0];
    bv[1] = bias[w * 32 + 16 + p0];

    #pragma unroll
    for (int mf = 0; mf < 2; ++mf)
        #pragma unroll
        for (int nf = 0; nf < 2; ++nf)
            #pragma unroll
            for (int j = 0; j < 4; ++j) {
                float v = acc[mf][nf][j] + (FUSED ? bv[nf] : h2f(xs[mf * 8 + nf * 4 + j]));
                v = (gate == 2) ? tanhf(v) : hsig(v);   // gate order i,f,g,o
                const int px = mf * 16 + g * 4 + j;
                gbuf[(gate * 32 + px) * 68 + chalf + nf * 16 + p0] = v;
            }
    __syncthreads();

    // ---- state update + BN output ----
    const int p  = tid >> 4;
    const int c4 = (tid & 15) * 4;
    const float4 iv = *(const float4*)&gbuf[(0 * 32 + p) * 68 + c4];
    const float4 fv = *(const float4*)&gbuf[(1 * 32 + p) * 68 + c4];
    const float4 gv = *(const float4*)&gbuf[(2 * 32 + p) * 68 + c4];
    const float4 ov = *(const float4*)&gbuf[(3 * 32 + p) * 68 + c4];
    const size_t gpix = (size_t)((n * 64 + y) * 64 + xh * 32 + p);
    const size_t sb = gpix * 64 + c4;
    const float4 cold = do_h ? *(const float4*)&cbuf[sb]
                             : make_float4(0.f, 0.f, 0.f, 0.f);
    const float4 scv  = *(const float4*)&bn[c4];
    const float4 shv  = *(const float4*)&bn[64 + c4];

    const float ivv[4] = {iv.x, iv.y, iv.z, iv.w};
    const float fvv[4] = {fv.x, fv.y, fv.z, fv.w};
    const float gvv[4] = {gv.x, gv.y, gv.z, gv.w};
    const float ovv[4] = {ov.x, ov.y, ov.z, ov.w};
    const float cov[4] = {cold.x, cold.y, cold.z, cold.w};
    const float scc[4] = {scv.x, scv.y, scv.z, scv.w};
    const float shh[4] = {shv.x, shv.y, shv.z, shv.w};

    float cnew[4], obuf[4];
    us4 hh;
    unsigned short* hhp = (unsigned short*)&hh;
    #pragma unroll
    for (int j = 0; j < 4; ++j) {
        const float cn = fvv[j] * cov[j] + ivv[j] * gvv[j];
        const float hn = ovv[j] * tanhf(cn);
        cnew[j] = cn;
        hhp[j] = f2h(hn);
        obuf[j] = hn * scc[j] + shh[j];
    }
    *(float4*)&cbuf[sb] = *(float4*)&cnew[0];
    *(us4*)&ho[sb]      = hh;
    const size_t ob = ((size_t)((n * TT + t) * 4096 + y * 64 + xh * 32 + p)) * 64 + c4;
    *(float4*)&out[ob] = *(float4*)&obuf[0];
}

extern "C" void kernel_launch(void* const* d_in, const int* in_sizes, int n_in,
                              void* d_out, int out_size, void* d_ws, size_t ws_size,
                              hipStream_t stream) {
    const float* x     = (const float*)d_in[0];
    const float* Wx    = (const float*)d_in[1];
    const float* Wh    = (const float*)d_in[2];
    const float* b     = (const float*)d_in[3];
    const float* gamma = (const float*)d_in[4];
    const float* beta  = (const float*)d_in[5];
    const float* mean  = (const float*)d_in[6];
    const float* var   = (const float*)d_in[7];
    float* out = (float*)d_out;
    char* ws = (char*)d_ws;

    unsigned short* Wc   = (unsigned short*)(ws);            // 589,824 B
    float*          bn   = (float*)(ws + 589824);            // 512 B
    unsigned short* hA   = (unsigned short*)(ws + 590336);   // 1 MB fp16
    float*          cbuf = (float*)(ws + 1638912);           // 2 MB fp32
    unsigned short* hB   = (unsigned short*)(ws + 3736064);  // 1 MB fp16
    unsigned short* xg   = (unsigned short*)(ws + 4784640);  // 67,108,864 B
    const size_t NEED = 4784640ull + 67108864ull;            // 71,893,504 B

    prep_kernel<<<1153, 256, 0, stream>>>(Wx, Wh, gamma, beta, mean, var, Wc, bn);

    if (ws_size >= NEED) {
        // t==0 fast path never reads hA/cbuf -> no state memset needed
        xconv_kernel<<<2048, 512, 0, stream>>>(x, Wc, b, xg);
        for (int t = 0; t < TT; ++t) {
            const bool even = (t & 1) == 0;
            convstep_kernel<0><<<256, 512, 0, stream>>>(
                x, even ? hA : hB, Wc, b, xg, cbuf, even ? hB : hA, bn, out, t);
        }
    } else {
        hipMemsetAsync(ws + 590336, 0, 3145728, stream);     // h0 + c0 = 0
        for (int t = 0; t < TT; ++t) {
            const bool even = (t & 1) == 0;
            convstep_kernel<1><<<256, 512, 0, stream>>>(
                x, even ? hA : hB, Wc, b, xg, cbuf, even ? hB : hA, bn, out, t);
        }
    }
}

// Round 18
// 196.705 us; speedup vs baseline: 1.1128x; 1.0115x over previous
//
#include <hip/hip_runtime.h>
#include <cstddef>

typedef __attribute__((ext_vector_type(8))) _Float16 half8;
typedef __attribute__((ext_vector_type(4))) float f32x4;
typedef __attribute__((ext_vector_type(4))) unsigned short us4;

#define TT 16
#define APAD 72                 // shorts per (row,col) slot: 144 B
#define A_TILE (3*34*APAD)      // step-kernel tile: 7344 shorts
#define CHUNK  8192             // shorts per 16KB weight chunk
#define NB     6                // B reg-pipeline slots
#define PF     5                // prefetch distance (< NB)
#define XNB    4                // B reg-pipeline slots (xconv)
#define XPF    3                // xconv prefetch distance (< XNB)

__device__ __forceinline__ unsigned short f2h(float f) {
    return __builtin_bit_cast(unsigned short, (_Float16)f);
}
__device__ __forceinline__ float h2f(unsigned short u) {
    return (float)__builtin_bit_cast(_Float16, u);
}
__device__ __forceinline__ float hsig(float z) {
    return fminf(fmaxf(0.2f * z + 0.5f, 0.f), 1.f);
}

// Weight pack (fp16): Wc short idx i = (s*4 + kg)*2048 + n*8 + j, s in [0,36)
// s<18 -> Wx chunk sub=s ; s>=18 -> Wh chunk sub=s-18
__global__ __launch_bounds__(256) void prep_kernel(
    const float* __restrict__ Wx, const float* __restrict__ Wh,
    const float* __restrict__ gamma, const float* __restrict__ beta,
    const float* __restrict__ mean, const float* __restrict__ var,
    unsigned short* __restrict__ Wc, float* __restrict__ bn)
{
    if (blockIdx.x == 1152) {
        if (threadIdx.x < 64) {
            const int c = threadIdx.x;
            const float inv = gamma[c] * rsqrtf(var[c] + 1e-3f);
            bn[c] = inv;
            bn[64 + c] = beta[c] - mean[c] * inv;
        }
        return;
    }
    const int i = blockIdx.x * 256 + threadIdx.x;   // < 294912
    const int j  = i & 7;
    const int n  = (i >> 3) & 255;
    const int kg = (i >> 11) & 3;
    const int s  = i >> 13;            // 0..35
    const int sub = s % 18;
    const float* W = (s >= 18) ? Wh : Wx;
    const int k5 = sub * 32 + kg * 8 + j;
    const int c = k5 & 63, q = k5 >> 6;
    const int kx = q % 3, ky = q / 3;
    Wc[i] = f2h(W[(size_t)((ky * 3 + kx) * 64 + c) * 256 + n]);
}

// B-frag register loads: chunk ci, this lane's pair (nf=0 at boff, nf=1 at +128)
#define BLOAD(slot, ci) {                                                     \
    const unsigned short* _p = Wc + (size_t)(ci) * CHUNK + boff;              \
    bp[slot][0] = *(const half8*)_p;                                          \
    bp[slot][1] = *(const half8*)(_p + 128);                                  \
}

// 18-chunk conv pass, B from reg pipeline.
template<int C0, int CLAST, int AOFF>
__device__ __forceinline__ void conv_pass18(
    const unsigned short* __restrict__ Wc, const int boff,
    half8 (&bp)[NB][2],
    const unsigned short* abase,
    f32x4 acc[2][2])
{
    #pragma unroll
    for (int sub = 0; sub < 18; ++sub) {
        const int ci = C0 + sub;
        if (ci + PF <= CLAST) BLOAD((ci + PF) % NB, ci + PF)

        const int ky = sub / 6, kx = (sub / 2) % 3, cb = sub & 1;
        const half8 b0 = bp[ci % NB][0];
        const half8 b1 = bp[ci % NB][1];
        const unsigned short* at = abase + AOFF + (ky * 34 + kx) * APAD + cb * 32;
        const half8 a0 = *(const half8*)(at);
        const half8 a1 = *(const half8*)(at + 16 * APAD);
        acc[0][0] = __builtin_amdgcn_mfma_f32_16x16x32_f16(a0, b0, acc[0][0], 0, 0, 0);
        acc[0][1] = __builtin_amdgcn_mfma_f32_16x16x32_f16(a0, b1, acc[0][1], 0, 0, 0);
        acc[1][0] = __builtin_amdgcn_mfma_f32_16x16x32_f16(a1, b0, acc[1][0], 0, 0, 0);
        acc[1][1] = __builtin_amdgcn_mfma_f32_16x16x32_f16(a1, b1, acc[1][1], 0, 0, 0);
    }
}

// Hoisted x-conv, 1 row/block. t>0 blocks: packed xg store. t==0 blocks: fused
// LSTM step (h0=c0=0) writing cbuf/h1/out directly — xg[t=0] never materialized.
// record vi = ((((n*16+t)*64+y)*2+xh)*8+w)*64+lane -> 16 shorts [mfc][nf][j].
__global__ __launch_bounds__(512) void xconv_kernel(
    const float* __restrict__ x,
    const unsigned short* __restrict__ Wc,
    const float* __restrict__ bias,
    unsigned short* __restrict__ xg,
    const float* __restrict__ bn,
    float* __restrict__ cbuf,
    unsigned short* __restrict__ h1,     // t=0 writes hB
    float* __restrict__ out)
{
    const int bid0 = blockIdx.x;
    const int bid = (bid0 & 7) * 256 + (bid0 >> 3);  // bijective XCD swizzle (2048=8*256)
    const int y = bid & 63;
    const int t = (bid >> 6) & 15;
    const int n = bid >> 10;
    const int tid = threadIdx.x, lane = tid & 63, w = tid >> 6;
    const int p0 = lane & 15, g = lane >> 4;

    // union: A tile [3][66][APAD] = 14256 shorts ; t0 gbuf [4][32][68] f32 = 17408 shorts
    __shared__ __align__(16) unsigned short smem[17408];

    const int boff = g * 2048 + (w * 32 + p0) * 8;

    half8 bp[XNB][2];
    #pragma unroll
    for (int sc = 0; sc < XPF; ++sc) BLOAD(sc, sc)

    // stage A tile rows y-1..y+1
    const float* __restrict__ xt = x + (size_t)(n * TT + t) * 4096 * 64;
    for (int idx = tid; idx < 3 * 66 * 8; idx += 512) {
        const int cg  = idx & 7;
        const int col = (idx >> 3) % 66;
        const int r   = (idx >> 3) / 66;
        const int gy = y + r - 1;
        const int gx = col - 1;
        const bool ok = ((unsigned)gy < 64u) && ((unsigned)gx < 64u);
        float4 v0 = make_float4(0.f, 0.f, 0.f, 0.f), v1 = v0;
        if (ok) {
            const float* p = xt + (size_t)(gy * 64 + gx) * 64 + cg * 8;
            v0 = *(const float4*)p;
            v1 = *(const float4*)(p + 4);
        }
        __align__(16) unsigned short os[8];
        os[0] = f2h(v0.x); os[1] = f2h(v0.y); os[2] = f2h(v0.z); os[3] = f2h(v0.w);
        os[4] = f2h(v1.x); os[5] = f2h(v1.y); os[6] = f2h(v1.z); os[7] = f2h(v1.w);
        *(uint4*)&smem[(r * 66 + col) * APAD + cg * 8] = *(const uint4*)os;
    }
    __syncthreads();

    const unsigned short* abase = smem + p0 * APAD + g * 8;

    // K-loop: 18 chunks (Wx), 4 m-frags (64 px), B from regs
    f32x4 acc[4][2] = {};
    #pragma unroll
    for (int sub = 0; sub < 18; ++sub) {
        if (sub + XPF < 18) BLOAD((sub + XPF) % XNB, sub + XPF)

        const int ky = sub / 6, kx = (sub / 2) % 3, cb = sub & 1;
        const half8 b0 = bp[sub % XNB][0];
        const half8 b1 = bp[sub % XNB][1];
        #pragma unroll
        for (int cq = 0; cq < 4; ++cq) {
            const half8 a = *(const half8*)(abase
                + (ky * 66 + cq * 16 + kx) * APAD + cb * 32);
            acc[cq][0] = __builtin_amdgcn_mfma_f32_16x16x32_f16(a, b0, acc[cq][0], 0, 0, 0);
            acc[cq][1] = __builtin_amdgcn_mfma_f32_16x16x32_f16(a, b1, acc[cq][1], 0, 0, 0);
        }
    }

    const float bv0 = bias[w * 32 + p0];
    const float bv1 = bias[w * 32 + 16 + p0];

    if (t != 0) {
        // packed xg store: 2 records (xh) of 32 B per lane; cq = xh*2 + mfc
        #pragma unroll
        for (int xh2 = 0; xh2 < 2; ++xh2) {
            unsigned short os[16];
            #pragma unroll
            for (int mfc = 0; mfc < 2; ++mfc)
                #pragma unroll
                for (int nf = 0; nf < 2; ++nf)
                    #pragma unroll
                    for (int j = 0; j < 4; ++j)
                        os[mfc * 8 + nf * 4 + j] =
                            f2h(acc[xh2 * 2 + mfc][nf][j] + (nf ? bv1 : bv0));
            const size_t vi = ((((size_t)(n * TT + t) * 64 + y) * 2 + xh2) * 8 + w) * 64 + lane;
            unsigned short* dst = xg + vi * 16;
            *(uint4*)dst       = *(uint4*)&os[0];
            *(uint4*)(dst + 8) = *(uint4*)&os[8];
        }
    } else {
        // fused t=0 LSTM step (h0=c0=0): proven gbuf pattern, two xh-half passes
        float* gbuf = (float*)smem;          // [4][32][68] f32, overlays A tile
        const int gate = w >> 1;
        const int chalf = (w & 1) * 32;
        #pragma unroll
        for (int xh2 = 0; xh2 < 2; ++xh2) {
            __syncthreads();                 // A-reads (iter0) / prev consume done
            #pragma unroll
            for (int mf = 0; mf < 2; ++mf)
                #pragma unroll
                for (int nf = 0; nf < 2; ++nf)
                    #pragma unroll
                    for (int j = 0; j < 4; ++j) {
                        float v = acc[xh2 * 2 + mf][nf][j] + (nf ? bv1 : bv0);
                        v = (gate == 2) ? tanhf(v) : hsig(v);   // order i,f,g,o
                        const int px = mf * 16 + g * 4 + j;
                        gbuf[(gate * 32 + px) * 68 + chalf + nf * 16 + p0] = v;
                    }
            __syncthreads();
            const int p  = tid >> 4;
            const int c4 = (tid & 15) * 4;
            const float4 iv = *(const float4*)&gbuf[(0 * 32 + p) * 68 + c4];
            const float4 gv = *(const float4*)&gbuf[(2 * 32 + p) * 68 + c4];
            const float4 ov = *(const float4*)&gbuf[(3 * 32 + p) * 68 + c4];
            const float ivv[4] = {iv.x, iv.y, iv.z, iv.w};
            const float gvv[4] = {gv.x, gv.y, gv.z, gv.w};
            const float ovv[4] = {ov.x, ov.y, ov.z, ov.w};
            const float4 scv = *(const float4*)&bn[c4];
            const float4 shv = *(const float4*)&bn[64 + c4];
            const float scc[4] = {scv.x, scv.y, scv.z, scv.w};
            const float shh[4] = {shv.x, shv.y, shv.z, shv.w};
            const size_t sb = ((size_t)((n * 64 + y) * 64 + xh2 * 32 + p)) * 64 + c4;
            float cnew[4], obuf[4];
            us4 hh;
            unsigned short* hhp = (unsigned short*)&hh;
            #pragma unroll
            for (int j = 0; j < 4; ++j) {
                const float cn = ivv[j] * gvv[j];          // f=..*0, c0=0
                const float hn = ovv[j] * tanhf(cn);
                cnew[j] = cn;
                hhp[j] = f2h(hn);
                obuf[j] = hn * scc[j] + shh[j];
            }
            *(float4*)&cbuf[sb] = *(float4*)&cnew[0];
            *(us4*)&h1[sb]      = hh;
            const size_t ob = ((size_t)((n * TT + 0) * 4096 + y * 64 + xh2 * 32 + p)) * 64 + c4;
            *(float4*)&out[ob] = *(float4*)&obuf[0];
        }
    }
}

// Per-timestep kernel. FUSED=1: full x+h conv (ws fallback). FUSED=0: h-conv + xg,
// t==0 fast path retained (unused in xg path now). Skips dead c/h stores at t=15.
// Block = (n,y,xhalf): 32 px x 256 ch, 8 waves.
template<int FUSED>
__global__ __launch_bounds__(512) void convstep_kernel(
    const float* __restrict__ x,
    const unsigned short* __restrict__ hb,
    const unsigned short* __restrict__ Wc,
    const float* __restrict__ bias,
    const unsigned short* __restrict__ xg,
    float* __restrict__ cbuf,
    unsigned short* __restrict__ ho,
    const float* __restrict__ bn,
    float* __restrict__ out,
    const int t)
{
    const int bid0 = blockIdx.x;
    const int bid = (bid0 & 7) * 32 + (bid0 >> 3);   // bijective XCD swizzle
    const int xh = bid & 1;
    const int y  = (bid >> 1) & 63;
    const int n  = bid >> 7;
    const int tid = threadIdx.x;
    const int lane = tid & 63;
    const int w = tid >> 6;
    const int p0 = lane & 15;
    const int g  = lane >> 4;

    // smem: A tiles; overlaid by gate buffer [4][32][68] f32 = 34816 B after K-loop
    constexpr int SMEM_SHORTS = FUSED ? (2 * A_TILE) : 17408;   // FUSED0: 34816 B
    __shared__ __align__(16) unsigned short smem[SMEM_SHORTS];

    const int boff = g * 2048 + (w * 32 + p0) * 8;
    const bool do_h = FUSED || (t > 0);     // wave-uniform

    // packed xg prefetch: one 32B record per lane
    unsigned short xs[16];
    if (!FUSED) {
        const size_t vi = ((((size_t)(n * TT + t) * 64 + y) * 2 + xh) * 8 + w) * 64 + lane;
        const uint4* xp = (const uint4*)(xg + vi * 16);
        *(uint4*)&xs[0] = xp[0];
        *(uint4*)&xs[8] = xp[1];
    }

    f32x4 acc[2][2] = {};
    if (do_h) {
        // B prologue into regs (latency hides under A-staging)
        constexpr int C0 = FUSED ? 0 : 18;
        half8 bp[NB][2];
        #pragma unroll
        for (int sc = 0; sc < PF; ++sc) BLOAD((C0 + sc) % NB, C0 + sc)

        // ---- stage A tiles: FUSED: x(tile0) + h(tile1); else h(tile0) ----
        constexpr int NTILE = FUSED ? 2 : 1;
        const float* __restrict__ xt = x + (size_t)(n * TT + t) * 4096 * 64;
        const size_t hbase = (size_t)n * 4096 * 64;
        for (int idx = tid; idx < NTILE * 3 * 34 * 8; idx += 512) {
            const int cg  = idx & 7;
            const int col = (idx >> 3) % 34;
            const int i3  = (idx >> 3) / 34;
            const int r   = i3 % 3;
            const int src = i3 / 3;
            const int gy = y + r - 1;
            const int gx = xh * 32 + col - 1;
            const bool ok = ((unsigned)gy < 64u) && ((unsigned)gx < 64u);
            const int ebase = (r * 34 + col) * APAD + cg * 8;
            if (FUSED && src == 0) {
                float4 v0 = make_float4(0.f, 0.f, 0.f, 0.f), v1 = v0;
                if (ok) {
                    const float* p = xt + (size_t)(gy * 64 + gx) * 64 + cg * 8;
                    v0 = *(const float4*)p;
                    v1 = *(const float4*)(p + 4);
                }
                __align__(16) unsigned short os[8];
                os[0] = f2h(v0.x); os[1] = f2h(v0.y); os[2] = f2h(v0.z); os[3] = f2h(v0.w);
                os[4] = f2h(v1.x); os[5] = f2h(v1.y); os[6] = f2h(v1.z); os[7] = f2h(v1.w);
                *(uint4*)&smem[ebase] = *(const uint4*)os;
            } else {
                uint4 v = make_uint4(0u, 0u, 0u, 0u);
                if (ok) v = *(const uint4*)(hb + hbase + (size_t)(gy * 64 + gx) * 64 + cg * 8);
                *(uint4*)&smem[(FUSED ? A_TILE : 0) + ebase] = v;
            }
        }
        __syncthreads();

        // ---- K-loop (B from reg pipeline, compiler-managed waits) ----
        const unsigned short* abase = smem + p0 * APAD + g * 8;
        if (FUSED) {
            conv_pass18<0, 35, 0>(Wc, boff, bp, abase, acc);
            conv_pass18<18, 35, A_TILE>(Wc, boff, bp, abase, acc);
        } else {
            conv_pass18<18, 35, 0>(Wc, boff, bp, abase, acc);
        }
    }

    // ---- gates -> LDS gate buffer (overlay A region) ----
    __syncthreads();
    float* gbuf = (float*)smem;            // [4][32][68] f32 = 34816 B
    const int gate = w >> 1;
    const int chalf = (w & 1) * 32;

    float bv[2];
    bv[0] = bias[w * 32 + p0];
    bv[1] = bias[w * 32 + 16 + p0];

    #pragma unroll
    for (int mf = 0; mf < 2; ++mf)
        #pragma unroll
        for (int nf = 0; nf < 2; ++nf)
            #pragma unroll
            for (int j = 0; j < 4; ++j) {
                float v = acc[mf][nf][j] + (FUSED ? bv[nf] : h2f(xs[mf * 8 + nf * 4 + j]));
                v = (gate == 2) ? tanhf(v) : hsig(v);   // gate order i,f,g,o
                const int px = mf * 16 + g * 4 + j;
                gbuf[(gate * 32 + px) * 68 + chalf + nf * 16 + p0] = v;
            }
    __syncthreads();

    // ---- state update + BN output ----
    const int p  = tid >> 4;
    const int c4 = (tid & 15) * 4;
    const float4 iv = *(const float4*)&gbuf[(0 * 32 + p) * 68 + c4];
    const float4 fv = *(const float4*)&gbuf[(1 * 32 + p) * 68 + c4];
    const float4 gv = *(const float4*)&gbuf[(2 * 32 + p) * 68 + c4];
    const float4 ov = *(const float4*)&gbuf[(3 * 32 + p) * 68 + c4];
    const size_t gpix = (size_t)((n * 64 + y) * 64 + xh * 32 + p);
    const size_t sb = gpix * 64 + c4;
    const float4 cold = do_h ? *(const float4*)&cbuf[sb]
                             : make_float4(0.f, 0.f, 0.f, 0.f);
    const float4 scv  = *(const float4*)&bn[c4];
    const float4 shv  = *(const float4*)&bn[64 + c4];

    const float ivv[4] = {iv.x, iv.y, iv.z, iv.w};
    const float fvv[4] = {fv.x, fv.y, fv.z, fv.w};
    const float gvv[4] = {gv.x, gv.y, gv.z, gv.w};
    const float ovv[4] = {ov.x, ov.y, ov.z, ov.w};
    const float cov[4] = {cold.x, cold.y, cold.z, cold.w};
    const float scc[4] = {scv.x, scv.y, scv.z, scv.w};
    const float shh[4] = {shv.x, shv.y, shv.z, shv.w};

    float cnew[4], obuf[4];
    us4 hh;
    unsigned short* hhp = (unsigned short*)&hh;
    #pragma unroll
    for (int j = 0; j < 4; ++j) {
        const float cn = fvv[j] * cov[j] + ivv[j] * gvv[j];
        const float hn = ovv[j] * tanhf(cn);
        cnew[j] = cn;
        hhp[j] = f2h(hn);
        obuf[j] = hn * scc[j] + shh[j];
    }
    if (t != TT - 1) {                      // c16/h16 are dead
        *(float4*)&cbuf[sb] = *(float4*)&cnew[0];
        *(us4*)&ho[sb]      = hh;
    }
    const size_t ob = ((size_t)((n * TT + t) * 4096 + y * 64 + xh * 32 + p)) * 64 + c4;
    *(float4*)&out[ob] = *(float4*)&obuf[0];
}

extern "C" void kernel_launch(void* const* d_in, const int* in_sizes, int n_in,
                              void* d_out, int out_size, void* d_ws, size_t ws_size,
                              hipStream_t stream) {
    const float* x     = (const float*)d_in[0];
    const float* Wx    = (const float*)d_in[1];
    const float* Wh    = (const float*)d_in[2];
    const float* b     = (const float*)d_in[3];
    const float* gamma = (const float*)d_in[4];
    const float* beta  = (const float*)d_in[5];
    const float* mean  = (const float*)d_in[6];
    const float* var   = (const float*)d_in[7];
    float* out = (float*)d_out;
    char* ws = (char*)d_ws;

    unsigned short* Wc   = (unsigned short*)(ws);            // 589,824 B
    float*          bn   = (float*)(ws + 589824);            // 512 B
    unsigned short* hA   = (unsigned short*)(ws + 590336);   // 1 MB fp16
    float*          cbuf = (float*)(ws + 1638912);           // 2 MB fp32
    unsigned short* hB   = (unsigned short*)(ws + 3736064);  // 1 MB fp16
    unsigned short* xg   = (unsigned short*)(ws + 4784640);  // 67,108,864 B
    const size_t NEED = 4784640ull + 67108864ull;            // 71,893,504 B

    prep_kernel<<<1153, 256, 0, stream>>>(Wx, Wh, gamma, beta, mean, var, Wc, bn);

    if (ws_size >= NEED) {
        // xconv fuses the t=0 step (writes cbuf, hB, out[t=0]); no state memset
        xconv_kernel<<<2048, 512, 0, stream>>>(x, Wc, b, xg, bn, cbuf, hB, out);
        for (int t = 1; t < TT; ++t) {
            const bool even = (t & 1) == 0;
            convstep_kernel<0><<<256, 512, 0, stream>>>(
                x, even ? hA : hB, Wc, b, xg, cbuf, even ? hB : hA, bn, out, t);
        }
    } else {
        hipMemsetAsync(ws + 590336, 0, 3145728, stream);     // h0 + c0 = 0
        for (int t = 0; t < TT; ++t) {
            const bool even = (t & 1) == 0;
            convstep_kernel<1><<<256, 512, 0, stream>>>(
                x, even ? hA : hB, Wc, b, xg, cbuf, even ? hB : hA, bn, out, t);
        }
    }
}